// Round 1
// baseline (12795.552 us; speedup 1.0000x reference)
//
#include <hip/hip_runtime.h>

#define B_   64
#define T_   256
#define IN_  256
#define U_   768
#define C3_  2304   // 3*U
#define OUT_ 64
#define NWG  256
#define NTH  512
#define KCH  128    // per-wave K chunk (waves 0,1: x K=256; waves 2..7: h K=768)
#define UPW  3      // u columns per WG (256*3 = 768)

#define H_ELEMS (B_ * U_)
#define WS_BYTES (2 * H_ELEMS * 4 + 64)

__device__ __forceinline__ void grid_barrier(unsigned* bar, unsigned target) {
  __syncthreads();                      // each wave drains its stores (vmcnt0) before s_barrier
  if (threadIdx.x == 0) {
    __threadfence();                    // release: write back dirty L2 so other XCDs see h_new
    __hip_atomic_fetch_add(bar, 1u, __ATOMIC_RELEASE, __HIP_MEMORY_SCOPE_AGENT);
    while (__hip_atomic_load(bar, __ATOMIC_ACQUIRE, __HIP_MEMORY_SCOPE_AGENT) < target) {
      __builtin_amdgcn_s_sleep(1);
    }
    __threadfence();                    // acquire: invalidate stale L1/L2 lines
  }
  __syncthreads();
}

__global__ void __launch_bounds__(NTH, 1) gru_fused(
    const float* __restrict__ x, const float* __restrict__ kern,
    const float* __restrict__ rec, const float* __restrict__ bias,
    const float* __restrict__ w_out, const float* __restrict__ b_out,
    float* __restrict__ out, float* __restrict__ ws)
{
  float* hbuf0 = ws;
  float* hbuf1 = ws + H_ELEMS;
  unsigned* bar = (unsigned*)(ws + 2 * H_ELEMS);

  __shared__ float wlds[8][KCH][12];   // weight slice, 12-padded rows (48 KB)
  __shared__ float part[8][B_][9];     // per-wave partial dots (18 KB)

  const int wg  = blockIdx.x;
  const int tid = threadIdx.x;
  const int b   = tid & 63;
  const int j   = __builtin_amdgcn_readfirstlane(tid >> 6); // wave id (uniform)
  const int mg  = tid >> 6;                                  // gate-phase m index
  const int u0  = wg * UPW;

  // ---- stage this WG's weight slice into LDS (once) ----
  {
    const float* src = (j < 2) ? (kern + (size_t)(j * KCH) * C3_)
                               : (rec  + (size_t)((j - 2) * KCH) * C3_);
    for (int kk = b; kk < KCH; kk += 64) {
      const float* row = src + (size_t)kk * C3_ + u0;
      #pragma unroll
      for (int g = 0; g < 3; ++g)
        #pragma unroll
        for (int m = 0; m < 3; ++m)
          wlds[j][kk][g * 3 + m] = row[g * U_ + m];
    }
  }

  // ---- hoist biases for gate threads (tid<192: one (b,u) pair each) ----
  float bz_i = 0.f, br_i = 0.f, bh_i = 0.f, bz_r = 0.f, br_r = 0.f, bh_r = 0.f;
  if (tid < 192) {
    int u = u0 + mg;
    bz_i = bias[u];         br_i = bias[U_ + u];         bh_i = bias[2 * U_ + u];
    bz_r = bias[C3_ + u];   br_r = bias[C3_ + U_ + u];   bh_r = bias[C3_ + 2 * U_ + u];
  }
  float hreg = 0.f;  // this thread's owned h[b][u0+mg], exact fp32 across steps
  __syncthreads();

  const float* xrow = x + ((size_t)b * T_) * IN_;

  for (int t = 0; t < T_; ++t) {
    const float* hcur = (t & 1) ? hbuf1 : hbuf0;
    float*       hnxt = (t & 1) ? hbuf0 : hbuf1;

    float acc0=0,acc1=0,acc2=0,acc3=0,acc4=0,acc5=0,acc6=0,acc7=0,acc8=0;
    const float* a = (j < 2) ? (xrow + (size_t)t * IN_ + j * KCH)
                             : (hcur + (size_t)b * U_ + (j - 2) * KCH);
    #pragma unroll 4
    for (int kk = 0; kk < KCH; ++kk) {
      float av = a[kk];
      const float* wr = &wlds[j][kk][0];
      float4 w0 = *(const float4*)(wr);
      float4 w1 = *(const float4*)(wr + 4);
      float  w2 = wr[8];
      acc0 += av * w0.x; acc1 += av * w0.y; acc2 += av * w0.z;
      acc3 += av * w0.w; acc4 += av * w1.x; acc5 += av * w1.y;
      acc6 += av * w1.z; acc7 += av * w1.w; acc8 += av * w2;
    }
    part[j][b][0]=acc0; part[j][b][1]=acc1; part[j][b][2]=acc2;
    part[j][b][3]=acc3; part[j][b][4]=acc4; part[j][b][5]=acc5;
    part[j][b][6]=acc6; part[j][b][7]=acc7; part[j][b][8]=acc8;
    __syncthreads();

    if (tid < 192) {
      float xz = part[0][b][mg]     + part[1][b][mg];
      float xr = part[0][b][3 + mg] + part[1][b][3 + mg];
      float xh = part[0][b][6 + mg] + part[1][b][6 + mg];
      float iz = 0.f, ir = 0.f, ih = 0.f;
      #pragma unroll
      for (int p = 2; p < 8; ++p) {
        iz += part[p][b][mg]; ir += part[p][b][3 + mg]; ih += part[p][b][6 + mg];
      }
      xz += bz_i; xr += br_i; xh += bh_i;
      iz += bz_r; ir += br_r; ih += bh_r;
      float z  = 1.f / (1.f + __expf(-(xz + iz)));
      float r  = 1.f / (1.f + __expf(-(xr + ir)));
      float hh = fmaxf(0.f, xh + r * ih);           // reset_after: r applied to recurrent part
      float hn = z * hreg + (1.f - z) * hh;
      hreg = hn;
      hnxt[(size_t)b * U_ + u0 + mg] = hn;
    }
    grid_barrier(bar, (unsigned)(t + 1) * NWG);
  }

  // ---- dense tail: out = h_last @ w_out + b_out ; h_last is hbuf0 (t=255 wrote it) ----
  if (wg < B_) {
    const float* hl = hbuf0 + (size_t)wg * U_;
    const int o  = tid & 63;
    const int kb = j * 96;                 // 768 = 8 waves * 96
    float acc = 0.f;
    for (int k = kb; k < kb + 96; ++k)
      acc += hl[k] * w_out[(size_t)k * OUT_ + o];
    float* pd = &part[0][0][0];
    pd[j * 64 + o] = acc;
    __syncthreads();
    if (j == 0) {
      float s = 0.f;
      #pragma unroll
      for (int p = 0; p < 8; ++p) s += pd[p * 64 + o];
      out[(size_t)wg * OUT_ + o] = s + b_out[o];
    }
  }
}

extern "C" void kernel_launch(void* const* d_in, const int* in_sizes, int n_in,
                              void* d_out, int out_size, void* d_ws, size_t ws_size,
                              hipStream_t stream) {
  const float* x     = (const float*)d_in[0];
  const float* kern  = (const float*)d_in[1];
  const float* rec   = (const float*)d_in[2];
  const float* bias  = (const float*)d_in[3];
  const float* w_out = (const float*)d_in[4];
  const float* b_out = (const float*)d_in[5];
  float* outp = (float*)d_out;
  float* ws   = (float*)d_ws;

  // zero h0 (h init) and the barrier counter every launch (deterministic)
  hipMemsetAsync(d_ws, 0, WS_BYTES, stream);

  void* args[] = {(void*)&x, (void*)&kern, (void*)&rec, (void*)&bias,
                  (void*)&w_out, (void*)&b_out, (void*)&outp, (void*)&ws};
  hipLaunchCooperativeKernel(reinterpret_cast<void*>(&gru_fused),
                             dim3(NWG), dim3(NTH), args, 0u, stream);
}

// Round 2
// 8047.008 us; speedup vs baseline: 1.5901x; 1.5901x over previous
//
#include <hip/hip_runtime.h>

#define B_   64
#define T_   256
#define IN_  256
#define U_   768
#define C3_  2304   // 3*U
#define OUT_ 64
#define NWG  256
#define NTH  1024
#define XWV  4      // waves 0..3: x-projection (K=256, 64 each)
#define UPW  3      // u columns per WG

#define H_ELEMS (U_ * B_)          // h stored transposed: [U][B]
#define WS_BYTES (2 * H_ELEMS * 4 + 2048)

// xs swizzle: float4-unit index cu in row `row` lives at cu ^ (row&15) ^ ((row>>2)&12)
__device__ __forceinline__ int xswz(int cu, int row) {
  return cu ^ (row & 15) ^ ((row >> 2) & 12);
}

__device__ __forceinline__ float rdlane(float v, int lane) {
  return __uint_as_float(__builtin_amdgcn_readlane(__float_as_uint(v), lane));
}

__global__ void __launch_bounds__(NTH, 1) gru_fused(
    const float* __restrict__ x, const float* __restrict__ kern,
    const float* __restrict__ rec, const float* __restrict__ bias,
    const float* __restrict__ w_out, const float* __restrict__ b_out,
    float* __restrict__ out, float* __restrict__ ws)
{
  float* hbuf0 = ws;
  float* hbuf1 = ws + H_ELEMS;
  unsigned* barb = (unsigned*)(ws + 2 * H_ELEMS);  // [g*32] group counters, [256] root

  __shared__ float4 xs4[64 * 64];      // x slice [b][64 float4-units], swizzled (64 KB)
  __shared__ float part[16][B_][9];    // per-wave partials (36 KB)

  const int wg  = blockIdx.x;
  const int tid = threadIdx.x;
  const int l   = tid & 63;
  const int j   = __builtin_amdgcn_readfirstlane(tid >> 6);  // wave id
  const int u0  = wg * UPW;

  // ---- weights -> per-lane registers: lane l holds k-row (j*64+l or rec row), 9 cols ----
  float wreg[9];
  {
    const float* wsrc = (j < XWV)
        ? (kern + (size_t)(j * 64 + l) * C3_ + u0)
        : (rec  + (size_t)((j - XWV) * 64 + l) * C3_ + u0);
    #pragma unroll
    for (int g = 0; g < 3; ++g)
      #pragma unroll
      for (int m = 0; m < 3; ++m)
        wreg[g * 3 + m] = wsrc[(size_t)g * U_ + m];
  }

  // ---- gate-thread bias hoist (tid<192: one (b,u) each; b=l, mg=tid>>6) ----
  const int mg = tid >> 6;
  float bzi=0, bri=0, bhi=0, bzr=0, brr=0, bhr=0, hreg = 0.f;
  if (tid < 192) {
    int u = u0 + mg;
    bzi = bias[u];        bri = bias[U_ + u];        bhi = bias[2 * U_ + u];
    bzr = bias[C3_ + u];  brr = bias[C3_ + U_ + u];  bhr = bias[C3_ + 2 * U_ + u];
  }
  __syncthreads();

  for (int t = 0; t < T_; ++t) {
    const float* hcur = (t & 1) ? hbuf1 : hbuf0;
    float*       hnxt = (t & 1) ? hbuf0 : hbuf1;

    // ---- stage x[:, t, :] into LDS: wave j stages rows {j,16+j,32+j,48+j}, coalesced ----
    #pragma unroll
    for (int p = 0; p < 4; ++p) {
      int row = p * 16 + j;
      float4 v = ((const float4*)(x + (size_t)row * T_ * IN_ + (size_t)t * IN_))[l];
      xs4[row * 64 + xswz(l, row)] = v;
    }
    __syncthreads();

    // ---- per-wave partial GEMV into part[j][b][9] ----
    float acc[9] = {0,0,0,0,0,0,0,0,0};
    if (j < XWV) {
      // x-projection: read xs from LDS (conflict-free swizzled b128)
      #pragma unroll 4
      for (int kk4 = 0; kk4 < 16; ++kk4) {
        float4 xv = xs4[l * 64 + xswz(j * 16 + kk4, l)];
        #pragma unroll
        for (int s = 0; s < 4; ++s) {
          float hv = (s == 0) ? xv.x : (s == 1) ? xv.y : (s == 2) ? xv.z : xv.w;
          int kk = kk4 * 4 + s;
          #pragma unroll
          for (int c = 0; c < 9; ++c) acc[c] += rdlane(wreg[c], kk) * hv;
        }
      }
    } else {
      // recurrent: coalesced global reads of h [U][B]
      const float* hc = hcur + (size_t)(j - XWV) * 64 * 64 + l;
      #pragma unroll 8
      for (int kk = 0; kk < 64; ++kk) {
        float hv = hc[(size_t)kk * 64];
        #pragma unroll
        for (int c = 0; c < 9; ++c) acc[c] += rdlane(wreg[c], kk) * hv;
      }
    }
    #pragma unroll
    for (int c = 0; c < 9; ++c) part[j][l][c] = acc[c];
    __syncthreads();

    // ---- gates (192 threads: b=l, u=u0+mg) ----
    if (tid < 192) {
      float xz=0, xr=0, xh=0, iz=0, ir=0, ih=0;
      #pragma unroll
      for (int p = 0; p < XWV; ++p) {
        xz += part[p][l][mg]; xr += part[p][l][3 + mg]; xh += part[p][l][6 + mg];
      }
      #pragma unroll
      for (int p = XWV; p < 16; ++p) {
        iz += part[p][l][mg]; ir += part[p][l][3 + mg]; ih += part[p][l][6 + mg];
      }
      xz += bzi; xr += bri; xh += bhi;
      iz += bzr; ir += brr; ih += bhr;
      float z  = 1.f / (1.f + __expf(-(xz + iz)));
      float r  = 1.f / (1.f + __expf(-(xr + ir)));
      float hh = fmaxf(0.f, xh + r * ih);      // reset_after: r on recurrent part only
      float hn = z * hreg + (1.f - z) * hh;
      hreg = hn;
      hnxt[(size_t)(u0 + mg) * 64 + l] = hn;   // [U][B]: coalesced 256B per mg
    }

    // ---- grid barrier: two-level counters, single release/acquire fences, relaxed spin ----
    __syncthreads();
    if (tid == 0) {
      __builtin_amdgcn_fence(__ATOMIC_RELEASE, "agent");       // wb L2 once
      unsigned old = __hip_atomic_fetch_add(&barb[(wg & 7) << 5], 1u,
                                            __ATOMIC_RELAXED, __HIP_MEMORY_SCOPE_AGENT);
      if (old == (unsigned)(t * 32 + 31))                       // 32nd arrival in group
        __hip_atomic_fetch_add(&barb[256], 1u,
                               __ATOMIC_RELAXED, __HIP_MEMORY_SCOPE_AGENT);
      unsigned tgt = (unsigned)(8 * (t + 1));
      while (__hip_atomic_load(&barb[256], __ATOMIC_RELAXED,
                               __HIP_MEMORY_SCOPE_AGENT) < tgt)
        __builtin_amdgcn_s_sleep(2);
      __builtin_amdgcn_fence(__ATOMIC_ACQUIRE, "agent");       // inv L1/L2 once
    }
    __syncthreads();
  }

  // ---- dense tail: out[b] = h_last @ w_out + b_out ; h_last = hbuf0 ([U][B]) ----
  if (wg < B_) {
    const int o  = tid & 63;
    const int kb = j * 48;                  // 768 = 16 waves * 48
    float a = 0.f;
    for (int k = kb; k < kb + 48; ++k)
      a += hbuf0[(size_t)k * 64 + wg] * w_out[(size_t)k * OUT_ + o];
    float* pd = &part[0][0][0];
    pd[j * 64 + o] = a;
    __syncthreads();
    if (j == 0) {
      float s = 0.f;
      #pragma unroll
      for (int p = 0; p < 16; ++p) s += pd[p * 64 + o];
      out[(size_t)wg * OUT_ + o] = s + b_out[o];
    }
  }
}

extern "C" void kernel_launch(void* const* d_in, const int* in_sizes, int n_in,
                              void* d_out, int out_size, void* d_ws, size_t ws_size,
                              hipStream_t stream) {
  const float* x     = (const float*)d_in[0];
  const float* kern  = (const float*)d_in[1];
  const float* rec   = (const float*)d_in[2];
  const float* bias  = (const float*)d_in[3];
  const float* w_out = (const float*)d_in[4];
  const float* b_out = (const float*)d_in[5];
  float* outp = (float*)d_out;
  float* ws   = (float*)d_ws;

  hipMemsetAsync(d_ws, 0, WS_BYTES, stream);   // h0 = 0, barrier counters = 0

  void* args[] = {(void*)&x, (void*)&kern, (void*)&rec, (void*)&bias,
                  (void*)&w_out, (void*)&b_out, (void*)&outp, (void*)&ws};
  hipLaunchCooperativeKernel(reinterpret_cast<void*>(&gru_fused),
                             dim3(NWG), dim3(NTH), args, 0u, stream);
}